// Round 11
// baseline (177.748 us; speedup 1.0000x reference)
//
#include <hip/hip_runtime.h>

// ISTFT: B=64, FRAMES=512, BINS=513, FFT_LEN=1024, STRIDE=256
// out: (64, 130816) fp32
#define BATCH    64
#define FRAMES   512
#define BINS     513
#define OUT_LEN  130816            // 256*511
#define HOPS_PER_BLOCK 13          // owned output hops; frames needed = 13+3 = 16 waves

__device__ __forceinline__ float2 cadd(float2 a, float2 b){ return make_float2(a.x+b.x, a.y+b.y); }
__device__ __forceinline__ float2 csub(float2 a, float2 b){ return make_float2(a.x-b.x, a.y-b.y); }
__device__ __forceinline__ float2 cmul(float2 a, float2 b){
    return make_float2(a.x*b.x - a.y*b.y, a.x*b.y + a.y*b.x);
}
// e^{2*pi*i*t}, t in REVOLUTIONS, t in [0,1): raw v_sin/v_cos, no range reduction
__device__ __forceinline__ float2 cexp_rev(float t){
    return make_float2(__builtin_amdgcn_cosf(t), __builtin_amdgcn_sinf(t));
}
// LDS pad: +1 float2 every 16
__device__ __forceinline__ int phys(int i){ return i + (i >> 4); }

// 8-point inverse DFT (positive twiddle sign), in place.
__device__ __forceinline__ void bfly8(float2 v[8]) {
    float2 t0 = cadd(v[0], v[4]), t1 = csub(v[0], v[4]);
    float2 t2 = cadd(v[2], v[6]), t3 = csub(v[2], v[6]);
    float2 E0 = cadd(t0, t2), E2 = csub(t0, t2);
    float2 E1 = make_float2(t1.x - t3.y, t1.y + t3.x);   // t1 + i*t3
    float2 E3 = make_float2(t1.x + t3.y, t1.y - t3.x);   // t1 - i*t3
    float2 u0 = cadd(v[1], v[5]), u1 = csub(v[1], v[5]);
    float2 u2 = cadd(v[3], v[7]), u3 = csub(v[3], v[7]);
    float2 O0 = cadd(u0, u2), O2 = csub(u0, u2);
    float2 O1 = make_float2(u1.x - u3.y, u1.y + u3.x);
    float2 O3 = make_float2(u1.x + u3.y, u1.y - u3.x);
    const float C = 0.70710678118654752440f;
    float2 w1 = make_float2(C*(O1.x - O1.y),  C*(O1.x + O1.y));   // W8^1 * O1
    float2 w2 = make_float2(-O2.y, O2.x);                         // i * O2
    float2 w3 = make_float2(-C*(O3.x + O3.y), C*(O3.x - O3.y));   // W8^3 * O3
    v[0] = cadd(E0, O0); v[4] = csub(E0, O0);
    v[1] = cadd(E1, w1); v[5] = csub(E1, w1);
    v[2] = cadd(E2, w2); v[6] = csub(E2, w2);
    v[3] = cadd(E3, w3); v[7] = csub(E3, w3);
}

// Block = 16 waves, wave w computes frame f = u0-1+w fully wave-private
// (registers + its own in-place LDS buffer, ZERO extra barriers), then one
// __syncthreads and a cross-wave gather with paired b64 loads/stores.
// Round-11 = round-3 base (57.2us, best) with ONE delta: pack twiddles via
// compile-time 16th-root constants -- tk[j] = tk0 * e^{2pi i j/16} (literal
// float2), tk[j>=4] = i*tk[j-4] (signs fold into FMAs). 1 cexp + 3 depth-1
// INDEPENDENT cmuls replace 8 cexp (~88 VALU-cyc/thread, ~5%). This exact
// pack block passed correctness in R1 and R7; R7's regression was its
// depth-7 STAGE chains, which are NOT taken -- stages keep independent cexp.
// R10's LDS-staged load path reverted (bank conflicts +52%, regressed).
__global__ __launch_bounds__(1024, 8) void istft_kernel(
    const float* __restrict__ re_g, const float* __restrict__ im_g,
    float* __restrict__ out)
{
    __shared__ float2 Xbuf[16][544];            // phys(511) = 542 max
    __shared__ __align__(16) float win[1024];   // hann/1.5/1024 (irfft scale folded)

    const int tid  = threadIdx.x;
    const int wave = tid >> 6;
    const int lane = tid & 63;
    const int b    = blockIdx.y;
    const int u0   = blockIdx.x * HOPS_PER_BLOCK;
    const int f    = u0 - 1 + wave;                 // frame this wave computes
    const bool valid = (f >= 0) && (f < FRAMES);

    // ---- issue the global loads; win + twiddle setup run under latency ----
    float ar[8], ai[8], cr[8], ci[8];
    if (valid) {
        const long long off = (long long)(b * FRAMES + f) * BINS;
        const float* re = re_g + off;
        const float* im = im_g + off;
        #pragma unroll
        for (int j = 0; j < 8; ++j) {
            const int k = lane + 64*j;
            ar[j] = re[k];
            ai[j] = im[k];
            cr[j] = re[512 - k];
            ci[j] = im[512 - k];
        }
    }

    // win[m] = (0.5 - 0.5 cos(2 pi m/1024)) * (2/3) * (1/1024)
    win[tid] = (0.5f - 0.5f * __builtin_amdgcn_cosf((float)tid * (1.0f/1024.0f)))
               * (2.0f / 3.0f / 1024.0f);

    float2* Xb = Xbuf[wave];

    if (valid) {
        // ---- Hermitian pack into stage-1 registers ----
        // v[j] = Z[l+64j] (unscaled), Z[k] = S + i*t*D,
        // S = X[k]+conj(X[512-k]), D = X[k]-conj(X[512-k]), t = e^{2pi i k/1024}
        // tk[j] = tk0 * C16^j for j<4 (C16^j compile-time const, independent
        // depth-1 cmuls); tk[j>=4] = i*tk[j-4] (folds into FMA signs).
        float2 tkb[4];
        tkb[0] = cexp_rev((float)lane * (1.0f/1024.0f));
        {
            const float Ca = 0.92387953251128675613f;   // cos(2pi/16)
            const float Cb = 0.38268343236508977173f;   // sin(2pi/16)
            const float Cq = 0.70710678118654752440f;
            tkb[1] = cmul(tkb[0], make_float2(Ca, Cb));
            tkb[2] = cmul(tkb[0], make_float2(Cq, Cq));
            tkb[3] = cmul(tkb[0], make_float2(Cb, Ca));
        }
        float2 v[8];
        #pragma unroll
        for (int j = 0; j < 8; ++j) {
            const int k = lane + 64*j;
            float xar = ar[j];
            float xai = (k == 0) ? 0.0f : ai[j];         // irfft ignores Im(DC)
            float xcr = cr[j];
            float xci = (k == 0) ? 0.0f : ci[j];         // Im(Nyquist) ignored
            float Sx = xar + xcr, Sy = xai - xci;
            float Dx = xar - xcr, Dy = xai + xci;
            const float2 tb = tkb[j & 3];
            const float2 tk = (j < 4) ? tb : make_float2(-tb.y, tb.x); // folds
            v[j].x = Sx - tk.x*Dy - tk.y*Dx;
            v[j].y = Sy + tk.x*Dx - tk.y*Dy;
        }

        // ---- 512-pt inverse FFT: 3 x radix-8 Stockham, in-place per wave ----
        // stage 1: v[r]=Z[l+64r] (in regs) -> Xb[8l+t] * e^{2pi i l t/512}
        bfly8(v);
        {
            const float lt = (float)lane * (1.0f/512.0f);
            int basei = phys(8*lane);                  // = 8l+(l>>1); t contiguous
            Xb[basei] = v[0];
            #pragma unroll
            for (int t = 1; t < 8; ++t)
                Xb[basei + t] = cmul(v[t], cexp_rev((float)t * lt));
        }
        // stage 2: read Xb[l+64r] -> write Xb[q+64p+8t] * e^{2pi i p t/64}
        // (same-wave DS ops processed in order; lockstep wave -> no barrier)
        {
            #pragma unroll
            for (int r = 0; r < 8; ++r) v[r] = Xb[phys(lane + 64*r)];
            bfly8(v);
            int p = lane >> 3, q = lane & 7;
            const float pf = (float)p * (1.0f/64.0f);
            Xb[phys(q + 64*p)] = v[0];
            #pragma unroll
            for (int t = 1; t < 8; ++t)
                Xb[phys(q + 64*p + 8*t)] = cmul(v[t], cexp_rev((float)t * pf));
        }
        // stage 3: read Xb[l+64r] -> write Xb[l+64t], no twiddle
        {
            #pragma unroll
            for (int r = 0; r < 8; ++r) v[r] = Xb[phys(lane + 64*r)];
            bfly8(v);
            #pragma unroll
            for (int t = 0; t < 8; ++t) Xb[phys(lane + 64*t)] = v[t];
        }
    }
    __syncthreads();   // the ONLY barrier: publish frame buffers + win table

    // ---- gather, paired: each thread makes outputs (2pi, 2pi+1) ----
    // out[256u+r] = sum_q win[r+256q] * x_{u+2-q}[r+256q];  with r even, the
    // Xbuf float2 at phys(m>>1) provides BOTH x[m] and x[m+1], and win[m..m+1]
    // reads as one aligned float2 -> half the DS ops, dwordx2 stores.
    const int nU    = min(HOPS_PER_BLOCK, (OUT_LEN/256) - u0);   // 511 hops total
    const int nPair = nU * 128;
    float2* outp2 = (float2*)(out + (long long)b * OUT_LEN + 256 * u0);
    const float2* win2 = (const float2*)win;
    for (int pi = tid; pi < nPair; pi += 1024) {
        int o0 = pi * 2;
        int r  = o0 & 255;                 // even
        int u  = u0 + (o0 >> 8);
        float s0 = 0.0f, s1 = 0.0f;
        #pragma unroll
        for (int qq = 0; qq < 4; ++qq) {
            int ff = u + 2 - qq;
            if (ff >= 0 && ff < FRAMES) {  // wave-uniform -> scalar branch
                int w = ff - u0 + 1;       // wave buffer index, 0..15
                int h = (r >> 1) + 128*qq; // == m>>1, m = r + 256q (even)
                float2 z  = Xbuf[w][phys(h)];
                float2 wn = win2[h & 511]; // win index m>>1; m<1024 so h<512
                s0 = fmaf(z.x, wn.x, s0);
                s1 = fmaf(z.y, wn.y, s1);
            }
        }
        outp2[pi] = make_float2(s0, s1);
    }
}

extern "C" void kernel_launch(void* const* d_in, const int* in_sizes, int n_in,
                              void* d_out, int out_size, void* d_ws, size_t ws_size,
                              hipStream_t stream) {
    const float* real = (const float*)d_in[0];
    const float* imag = (const float*)d_in[1];
    float* out = (float*)d_out;

    // 511 output hops per row, 13 per block -> 40 blocks per row
    dim3 grid((OUT_LEN/256 + HOPS_PER_BLOCK - 1) / HOPS_PER_BLOCK, BATCH);
    dim3 block(1024);
    istft_kernel<<<grid, block, 0, stream>>>(real, imag, out);
}

// Round 12
// 161.037 us; speedup vs baseline: 1.1038x; 1.1038x over previous
//
#include <hip/hip_runtime.h>

// ISTFT: B=64, FRAMES=512, BINS=513, FFT_LEN=1024, STRIDE=256
// out: (64, 130816) fp32
#define BATCH    64
#define FRAMES   512
#define BINS     513
#define OUT_LEN  130816            // 256*511
#define HOPS_PER_BLOCK 13          // owned output hops; frames needed = 13+3 = 16 waves

__device__ __forceinline__ float2 cadd(float2 a, float2 b){ return make_float2(a.x+b.x, a.y+b.y); }
__device__ __forceinline__ float2 csub(float2 a, float2 b){ return make_float2(a.x-b.x, a.y-b.y); }
__device__ __forceinline__ float2 cmul(float2 a, float2 b){
    return make_float2(a.x*b.x - a.y*b.y, a.x*b.y + a.y*b.x);
}
// e^{2*pi*i*t}, t in REVOLUTIONS, t in [0,1): raw v_sin/v_cos, no range reduction
__device__ __forceinline__ float2 cexp_rev(float t){
    return make_float2(__builtin_amdgcn_cosf(t), __builtin_amdgcn_sinf(t));
}
// LDS pad: +1 float2 every 16
__device__ __forceinline__ int phys(int i){ return i + (i >> 4); }

// 8-point inverse DFT (positive twiddle sign), in place.
__device__ __forceinline__ void bfly8(float2 v[8]) {
    float2 t0 = cadd(v[0], v[4]), t1 = csub(v[0], v[4]);
    float2 t2 = cadd(v[2], v[6]), t3 = csub(v[2], v[6]);
    float2 E0 = cadd(t0, t2), E2 = csub(t0, t2);
    float2 E1 = make_float2(t1.x - t3.y, t1.y + t3.x);   // t1 + i*t3
    float2 E3 = make_float2(t1.x + t3.y, t1.y - t3.x);   // t1 - i*t3
    float2 u0 = cadd(v[1], v[5]), u1 = csub(v[1], v[5]);
    float2 u2 = cadd(v[3], v[7]), u3 = csub(v[3], v[7]);
    float2 O0 = cadd(u0, u2), O2 = csub(u0, u2);
    float2 O1 = make_float2(u1.x - u3.y, u1.y + u3.x);
    float2 O3 = make_float2(u1.x + u3.y, u1.y - u3.x);
    const float C = 0.70710678118654752440f;
    float2 w1 = make_float2(C*(O1.x - O1.y),  C*(O1.x + O1.y));   // W8^1 * O1
    float2 w2 = make_float2(-O2.y, O2.x);                         // i * O2
    float2 w3 = make_float2(-C*(O3.x + O3.y), C*(O3.x - O3.y));   // W8^3 * O3
    v[0] = cadd(E0, O0); v[4] = csub(E0, O0);
    v[1] = cadd(E1, w1); v[5] = csub(E1, w1);
    v[2] = cadd(E2, w2); v[6] = csub(E2, w2);
    v[3] = cadd(E3, w3); v[7] = csub(E3, w3);
}

// Block = 16 waves, wave w computes frame f = u0-1+w fully wave-private
// (registers + its own in-place LDS buffer, ZERO extra barriers), then one
// __syncthreads and a cross-wave gather with paired b64 loads/stores.
// Round-12 = round-3 base (57.2us, best) with ONE delta, confined to the
// GATHER: the window values are computed in registers via quarter-turn trig
// identities -- win[m0+256q] = K(0.5 - 0.5 cos(th0 + q*pi/2)), and
// cos(th+q*pi/2) for q=0..3 is {cos,-sin,-cos,sin} (compile-time folds).
// 4 trans (idle pipe during gather) + 8 FMAs, computed ONCE per thread
// (h0 = tid&127 invariant across pi iterations), replace ALL 8 window
// ds_read_b64 per thread (~half the gather's LDS traffic). The win LDS
// table and its build are deleted (LDS 73728 -> 69632). The FFT phase --
// proven fragile (R7/R11: any twiddle restructuring regresses ~30%) -- is
// byte-identical to R3.
__global__ __launch_bounds__(1024, 8) void istft_kernel(
    const float* __restrict__ re_g, const float* __restrict__ im_g,
    float* __restrict__ out)
{
    __shared__ float2 Xbuf[16][544];            // phys(511) = 542 max

    const int tid  = threadIdx.x;
    const int wave = tid >> 6;
    const int lane = tid & 63;
    const int b    = blockIdx.y;
    const int u0   = blockIdx.x * HOPS_PER_BLOCK;
    const int f    = u0 - 1 + wave;                 // frame this wave computes
    const bool valid = (f >= 0) && (f < FRAMES);

    // ---- issue ALL 32 global loads first ----
    float ar[8], ai[8], cr[8], ci[8];
    if (valid) {
        const long long off = (long long)(b * FRAMES + f) * BINS;
        const float* re = re_g + off;
        const float* im = im_g + off;
        #pragma unroll
        for (int j = 0; j < 8; ++j) {
            const int k = lane + 64*j;
            ar[j] = re[k];
            ai[j] = im[k];
            cr[j] = re[512 - k];
            ci[j] = im[512 - k];
        }
    }

    float2* Xb = Xbuf[wave];

    if (valid) {
        // ---- Hermitian pack into stage-1 registers ----
        // v[j] = Z[l+64j] (unscaled), Z[k] = S + i*t*D,
        // S = X[k]+conj(X[512-k]), D = X[k]-conj(X[512-k]), t = e^{2pi i k/1024}
        const float a0 = (float)lane * (1.0f/1024.0f);
        float2 v[8];
        #pragma unroll
        for (int j = 0; j < 8; ++j) {
            const int k = lane + 64*j;
            float xar = ar[j];
            float xai = (k == 0) ? 0.0f : ai[j];         // irfft ignores Im(DC)
            float xcr = cr[j];
            float xci = (k == 0) ? 0.0f : ci[j];         // Im(Nyquist) ignored
            float Sx = xar + xcr, Sy = xai - xci;
            float Dx = xar - xcr, Dy = xai + xci;
            float2 tk = cexp_rev(a0 + (float)j * (1.0f/16.0f));  // exact dyadic arg
            v[j].x = Sx - tk.x*Dy - tk.y*Dx;
            v[j].y = Sy + tk.x*Dx - tk.y*Dy;
        }

        // ---- 512-pt inverse FFT: 3 x radix-8 Stockham, in-place per wave ----
        // stage 1: v[r]=Z[l+64r] (in regs) -> Xb[8l+t] * e^{2pi i l t/512}
        bfly8(v);
        {
            const float lt = (float)lane * (1.0f/512.0f);
            int basei = phys(8*lane);                  // = 8l+(l>>1); t contiguous
            Xb[basei] = v[0];
            #pragma unroll
            for (int t = 1; t < 8; ++t)
                Xb[basei + t] = cmul(v[t], cexp_rev((float)t * lt));
        }
        // stage 2: read Xb[l+64r] -> write Xb[q+64p+8t] * e^{2pi i p t/64}
        // (same-wave DS ops processed in order; lockstep wave -> no barrier)
        {
            #pragma unroll
            for (int r = 0; r < 8; ++r) v[r] = Xb[phys(lane + 64*r)];
            bfly8(v);
            int p = lane >> 3, q = lane & 7;
            const float pf = (float)p * (1.0f/64.0f);
            Xb[phys(q + 64*p)] = v[0];
            #pragma unroll
            for (int t = 1; t < 8; ++t)
                Xb[phys(q + 64*p + 8*t)] = cmul(v[t], cexp_rev((float)t * pf));
        }
        // stage 3: read Xb[l+64r] -> write Xb[l+64t], no twiddle
        {
            #pragma unroll
            for (int r = 0; r < 8; ++r) v[r] = Xb[phys(lane + 64*r)];
            bfly8(v);
            #pragma unroll
            for (int t = 0; t < 8; ++t) Xb[phys(lane + 64*t)] = v[t];
        }
    }
    __syncthreads();   // the ONLY barrier: publish frame buffers

    // ---- gather, paired: each thread makes outputs (2pi, 2pi+1) ----
    // out[256u+r] = sum_q win[r+256q] * x_{u+2-q}[r+256q]; r even, the Xbuf
    // float2 at phys(m>>1) provides BOTH x[m] and x[m+1]. Window values come
    // from registers: h0 = pi&127 is the same for both pi iterations, so one
    // set of 4 trans + 8 FMAs covers every window factor this thread needs.
    // win[m] = (0.5 - 0.5 cos(2pi m/1024)) * K, K = 2/3/1024 (irfft scale).
    const int nU    = min(HOPS_PER_BLOCK, (OUT_LEN/256) - u0);   // 511 hops total
    const int nPair = nU * 128;
    float2* outp2 = (float2*)(out + (long long)b * OUT_LEN + 256 * u0);

    float wnx[4], wny[4];
    {
        const float hK = 0.5f * (2.0f / 3.0f / 1024.0f);
        const int h0 = tid & 127;                  // = pi & 127 for both iters
        const float th0 = (float)(2*h0)     * (1.0f/1024.0f);
        const float th1 = (float)(2*h0 + 1) * (1.0f/1024.0f);
        const float c0 = __builtin_amdgcn_cosf(th0), sn0 = __builtin_amdgcn_sinf(th0);
        const float c1 = __builtin_amdgcn_cosf(th1), sn1 = __builtin_amdgcn_sinf(th1);
        // cos(th + q*pi/2) = {cos, -sin, -cos, sin}[q]
        wnx[0] = fmaf(-hK, c0,  hK);  wny[0] = fmaf(-hK, c1,  hK);
        wnx[1] = fmaf( hK, sn0, hK);  wny[1] = fmaf( hK, sn1, hK);
        wnx[2] = fmaf( hK, c0,  hK);  wny[2] = fmaf( hK, c1,  hK);
        wnx[3] = fmaf(-hK, sn0, hK);  wny[3] = fmaf(-hK, sn1, hK);
    }

    for (int pi = tid; pi < nPair; pi += 1024) {
        int o0 = pi * 2;
        int r  = o0 & 255;                 // even
        int u  = u0 + (o0 >> 8);
        float s0 = 0.0f, s1 = 0.0f;
        #pragma unroll
        for (int qq = 0; qq < 4; ++qq) {
            int ff = u + 2 - qq;
            if (ff >= 0 && ff < FRAMES) {  // wave-uniform -> scalar branch
                int w = ff - u0 + 1;       // wave buffer index, 0..15
                int h = (r >> 1) + 128*qq; // == m>>1, m = r + 256q (even)
                float2 z = Xbuf[w][phys(h)];
                s0 = fmaf(z.x, wnx[qq], s0);
                s1 = fmaf(z.y, wny[qq], s1);
            }
        }
        outp2[pi] = make_float2(s0, s1);
    }
}

extern "C" void kernel_launch(void* const* d_in, const int* in_sizes, int n_in,
                              void* d_out, int out_size, void* d_ws, size_t ws_size,
                              hipStream_t stream) {
    const float* real = (const float*)d_in[0];
    const float* imag = (const float*)d_in[1];
    float* out = (float*)d_out;

    // 511 output hops per row, 13 per block -> 40 blocks per row
    dim3 grid((OUT_LEN/256 + HOPS_PER_BLOCK - 1) / HOPS_PER_BLOCK, BATCH);
    dim3 block(1024);
    istft_kernel<<<grid, block, 0, stream>>>(real, imag, out);
}